// Round 17
// baseline (173.945 us; speedup 1.0000x reference)
//
#include <hip/hip_runtime.h>
#include <hip/hip_bf16.h>
#include <math.h>

#define EPSF 1e-6f

constexpr int Bc = 8;
constexpr int Nc = 4096;
constexpr int Dc = 512;
constexpr int QKVC = 3 * Dc;  // 1536

typedef __attribute__((ext_vector_type(8))) short short8v;
typedef __attribute__((ext_vector_type(8))) unsigned short ushort8v;
typedef __attribute__((ext_vector_type(4))) float float4v;
typedef __attribute__((ext_vector_type(16))) float float16v;

__device__ __forceinline__ unsigned short f2bf(float f) {
    union { float f; unsigned int u; } v; v.f = f;
    unsigned int u = v.u;
    return (unsigned short)((u + 0x7fffu + ((u >> 16) & 1u)) >> 16);
}
__device__ __forceinline__ float bf2f(unsigned short h) {
    union { unsigned int u; float f; } v; v.u = ((unsigned int)h) << 16;
    return v.f;
}

typedef __attribute__((address_space(1))) const void gvoid_t;
typedef __attribute__((address_space(3))) void lvoid_t;
__device__ __forceinline__ void llds16(const void* g, void* l) {
    __builtin_amdgcn_global_load_lds((gvoid_t*)g, (lvoid_t*)l, 16, 0, 0);
}

// ---------------------------------------------------------------------------
// f32 -> bf16 conversion, 8 elems/thread
// ---------------------------------------------------------------------------
__global__ __launch_bounds__(256) void cvt_f32_bf16(
    const float* __restrict__ in, unsigned short* __restrict__ out, int n8)
{
    int i = blockIdx.x * 256 + threadIdx.x;
    if (i >= n8) return;
    float4 a = reinterpret_cast<const float4*>(in)[2 * i];
    float4 b = reinterpret_cast<const float4*>(in)[2 * i + 1];
    ushort8v o;
    o[0] = f2bf(a.x); o[1] = f2bf(a.y); o[2] = f2bf(a.z); o[3] = f2bf(a.w);
    o[4] = f2bf(b.x); o[5] = f2bf(b.y); o[6] = f2bf(b.z); o[7] = f2bf(b.w);
    reinterpret_cast<ushort8v*>(out)[i] = o;
}

// combined weight convert: w_qkv (1536x512) then w_proj (512x512)
__global__ __launch_bounds__(256) void cvt_weights(
    const float* __restrict__ wq, const float* __restrict__ wp,
    unsigned short* __restrict__ wqo, unsigned short* __restrict__ wpo)
{
    const int i = blockIdx.x * 256 + threadIdx.x;
    const int NQ = 1536 * 512 / 8;            // 98304
    const float* src; unsigned short* dst; int idx;
    if (i < NQ) { src = wq; dst = wqo; idx = i; }
    else        { src = wp; dst = wpo; idx = i - NQ; }
    float4 a = reinterpret_cast<const float4*>(src)[2 * idx];
    float4 b = reinterpret_cast<const float4*>(src)[2 * idx + 1];
    ushort8v o;
    o[0] = f2bf(a.x); o[1] = f2bf(a.y); o[2] = f2bf(a.z); o[3] = f2bf(a.w);
    o[4] = f2bf(b.x); o[5] = f2bf(b.y); o[6] = f2bf(b.z); o[7] = f2bf(b.w);
    reinterpret_cast<ushort8v*>(dst)[idx] = o;
}

// ---------------------------------------------------------------------------
// qkv GEMM: ring-3 staging/sync VERBATIM (proven 83us), MFMA shape remapped
// 16x16x32 -> 32x32x16 (2382 vs 2075 TF ubench, ~15% less matrix-pipe time).
// Wave tile 64x64 = 2x2 frags of 32x32; BK=64 = 4 k-steps of 16.
// A/B frag: lane l -> row=l&31, k=(l>>5)*8+j (extends verified 16x16 pattern).
// C/D: col=lane&31, row=(reg&3)+8*(reg>>2)+4*(lane>>5)  [m74/m101 verified].
// ---------------------------------------------------------------------------
__global__ __launch_bounds__(512, 2) void gemm_qkv(
    const unsigned short* __restrict__ A,    // [32768,512]
    const unsigned short* __restrict__ Bm,   // [1536,512]
    unsigned short* __restrict__ Cout)       // [32768,1536]
{
    constexpr int LDA = 512, LDB = 512, LDC = 1536;
    constexpr int NT = 8;
    __shared__ unsigned short ring[3][24576];

    const int t = threadIdx.x;
    const int orig = blockIdx.x;
    const int wg = (orig & 7) * 192 + (orig >> 3);   // nwg=1536, %8==0
    const int bm = (wg / 12) * 256;
    const int bn = (wg % 12) * 128;

    const int w = t >> 6, lane = t & 63;
    const int l5 = lane & 31, g2 = lane >> 5;
    const int wr = (w >> 1) * 64;   // 4 M-waves
    const int wc = (w & 1) * 64;    // 2 N-waves

    const int rs = t >> 3;
    const int ci = t & 7;
    const int swz = ci ^ (rs & 7);
    const unsigned short* As0 = A + (size_t)(bm + rs) * LDA + swz * 8;
    const unsigned short* As1 = A + (size_t)(bm + 64 + rs) * LDA + swz * 8;
    const unsigned short* As2 = A + (size_t)(bm + 128 + rs) * LDA + swz * 8;
    const unsigned short* As3 = A + (size_t)(bm + 192 + rs) * LDA + swz * 8;
    const unsigned short* Bs0 = Bm + (size_t)(bn + rs) * LDB + swz * 8;
    const unsigned short* Bs1 = Bm + (size_t)(bn + 64 + rs) * LDB + swz * 8;

#define STAGEQ(Tt) do {                                                        \
        const int k0_ = (Tt) * 64;                                             \
        unsigned short* dA_ = &ring[(Tt) % 3][0];                              \
        unsigned short* dB_ = &ring[(Tt) % 3][16384];                          \
        llds16(As0 + k0_, dA_ + (size_t)t * 8);                                \
        llds16(As1 + k0_, dA_ + (size_t)(512 + t) * 8);                        \
        llds16(As2 + k0_, dA_ + (size_t)(1024 + t) * 8);                       \
        llds16(As3 + k0_, dA_ + (size_t)(1536 + t) * 8);                       \
        llds16(Bs0 + k0_, dB_ + (size_t)t * 8);                                \
        llds16(Bs1 + k0_, dB_ + (size_t)(512 + t) * 8);                        \
    } while (0)

    float16v acc[2][2];
#pragma unroll
    for (int i = 0; i < 2; ++i)
#pragma unroll
        for (int j = 0; j < 2; ++j)
#pragma unroll
            for (int r = 0; r < 16; ++r) acc[i][j][r] = 0.f;

    STAGEQ(0);
    STAGEQ(1);
    asm volatile("s_waitcnt vmcnt(6)" ::: "memory");
    __builtin_amdgcn_s_barrier();
    __builtin_amdgcn_sched_barrier(0);

#pragma unroll
    for (int T = 0; T < NT; ++T) {
        if (T + 2 < NT) STAGEQ(T + 2);

        const unsigned short* base = &ring[T % 3][0];
        short8v a[2][4], b[2][4];
#pragma unroll
        for (int fi = 0; fi < 2; ++fi)
#pragma unroll
            for (int ks = 0; ks < 4; ++ks) {
                const int row = wr + fi * 32 + l5;
                const int chunk = ks * 2 + g2;
                a[fi][ks] = *reinterpret_cast<const short8v*>(
                    base + row * 64 + ((chunk ^ (row & 7)) << 3));
            }
#pragma unroll
        for (int fj = 0; fj < 2; ++fj)
#pragma unroll
            for (int ks = 0; ks < 4; ++ks) {
                const int row = wc + fj * 32 + l5;
                const int chunk = ks * 2 + g2;
                b[fj][ks] = *reinterpret_cast<const short8v*>(
                    base + 16384 + row * 64 + ((chunk ^ (row & 7)) << 3));
            }

        __builtin_amdgcn_s_setprio(1);
#pragma unroll
        for (int ks = 0; ks < 4; ++ks)
#pragma unroll
            for (int fi = 0; fi < 2; ++fi)
#pragma unroll
                for (int fj = 0; fj < 2; ++fj)
                    acc[fi][fj] = __builtin_amdgcn_mfma_f32_32x32x16_bf16(
                        a[fi][ks], b[fj][ks], acc[fi][fj], 0, 0, 0);
        __builtin_amdgcn_s_setprio(0);

        if (T + 1 < NT) {
            if (T + 2 < NT)
                asm volatile("s_waitcnt vmcnt(6)" ::: "memory");
            else
                asm volatile("s_waitcnt vmcnt(0)" ::: "memory");
            __builtin_amdgcn_s_barrier();
            __builtin_amdgcn_sched_barrier(0);
        }
    }
#undef STAGEQ

    // epilogue: C/D layout col=lane&31, row=(reg&3)+8*(reg>>2)+4*g2
#pragma unroll
    for (int fi = 0; fi < 2; ++fi)
#pragma unroll
        for (int fj = 0; fj < 2; ++fj) {
            const int Cc = bn + wc + fj * 32 + l5;
            const bool do_elu = (Cc < 1024);
#pragma unroll
            for (int reg = 0; reg < 16; ++reg) {
                const int Rb = bm + wr + fi * 32 + (reg & 3) + 8 * (reg >> 2) + 4 * g2;
                float v = acc[fi][fj][reg];
                if (do_elu) v = (v > 0.f) ? (v + 1.0f + EPSF) : (expf(v) + EPSF);
                Cout[(size_t)Rb * LDC + Cc] = f2bf(v);
            }
        }
}

// ---------------------------------------------------------------------------
// kv partials v4 (round-15 proven): MFMA on transposed bf16 tiles
// ---------------------------------------------------------------------------
__global__ __launch_bounds__(256) void kv_part(
    const unsigned short* __restrict__ qkv,
    float* __restrict__ kvp, float* __restrict__ ksp)
{
    const int bh = blockIdx.x, chunk = blockIdx.y;
    const int b = bh >> 3, h = bh & 7;

    __shared__ unsigned short ktT[64 * 72];
    __shared__ unsigned short vtT[64 * 72];
    __shared__ float ksl[16][64];

    const int t = threadIdx.x;
    const int w = t >> 6, lane = t & 63;
    const int ln = lane & 15, g = lane >> 4;

    const bool isK = (t < 128);
    const int ts = isK ? t : t - 128;
    const int slot = ts & 7;
    const int ng = ts >> 3;

    const size_t base = ((size_t)b * Nc + (size_t)chunk * 512) * QKVC + h * 64
                      + (isK ? Dc : 2 * Dc) + (size_t)slot * 8;

    unsigned short* Tdst = isK ? ktT : vtT;

    float4v acc[4];
#pragma unroll
    for (int j = 0; j < 4; ++j) acc[j] = {0.f, 0.f, 0.f, 0.f};
    float ks8[8] = {};

    for (int it = 0; it < 8; ++it) {
        {
            const unsigned short* src = qkv + base + (size_t)(it * 64 + 4 * ng) * QKVC;
            ushort8v r0 = *reinterpret_cast<const ushort8v*>(src);
            ushort8v r1 = *reinterpret_cast<const ushort8v*>(src + QKVC);
            ushort8v r2 = *reinterpret_cast<const ushort8v*>(src + 2 * QKVC);
            ushort8v r3 = *reinterpret_cast<const ushort8v*>(src + 3 * QKVC);
#pragma unroll
            for (int i = 0; i < 8; ++i) {
                const int d = 8 * slot + i;
                unsigned long long pk = (unsigned long long)r0[i]
                    | ((unsigned long long)r1[i] << 16)
                    | ((unsigned long long)r2[i] << 32)
                    | ((unsigned long long)r3[i] << 48);
                *reinterpret_cast<unsigned long long*>(&Tdst[d * 72 + 4 * ng]) = pk;
                if (isK) ks8[i] += bf2f(r0[i]) + bf2f(r1[i]) + bf2f(r2[i]) + bf2f(r3[i]);
            }
        }
        __syncthreads();

        short8v afr[2], bfr[4][2];
#pragma unroll
        for (int kk = 0; kk < 2; ++kk)
            afr[kk] = *reinterpret_cast<const short8v*>(
                &ktT[(w * 16 + ln) * 72 + kk * 32 + g * 8]);
#pragma unroll
        for (int j = 0; j < 4; ++j)
#pragma unroll
            for (int kk = 0; kk < 2; ++kk)
                bfr[j][kk] = *reinterpret_cast<const short8v*>(
                    &vtT[(j * 16 + ln) * 72 + kk * 32 + g * 8]);
#pragma unroll
        for (int kk = 0; kk < 2; ++kk)
#pragma unroll
            for (int j = 0; j < 4; ++j)
                acc[j] = __builtin_amdgcn_mfma_f32_16x16x32_bf16(
                    afr[kk], bfr[j][kk], acc[j], 0, 0, 0);
        __syncthreads();
    }

    float* kvpp = kvp + ((size_t)bh * 8 + chunk) * 4096;
#pragma unroll
    for (int j = 0; j < 4; ++j)
#pragma unroll
        for (int r = 0; r < 4; ++r)
            kvpp[(w * 16 + g * 4 + r) * 64 + j * 16 + ln] = acc[j][r];

    if (isK) {
#pragma unroll
        for (int i = 0; i < 8; ++i) ksl[ng][8 * slot + i] = ks8[i];
    }
    __syncthreads();
    if (t < 64) {
        float s = 0.f;
#pragma unroll
        for (int c = 0; c < 16; ++c) s += ksl[c][t];
        ksp[((size_t)bh * 8 + chunk) * 64 + t] = s;
    }
}

// ---------------------------------------------------------------------------
// reduce 8 chunk-partials -> kvb (bf16, [d][e]) + ksum (f32)
// ---------------------------------------------------------------------------
__global__ __launch_bounds__(256) void kv_reduce(
    const float* __restrict__ kvp, const float* __restrict__ ksp,
    unsigned short* __restrict__ kvb, float* __restrict__ ksum)
{
    const int bh = blockIdx.x, t = threadIdx.x;
    const float* src = kvp + (size_t)bh * 8 * 4096;
#pragma unroll
    for (int i = 0; i < 16; ++i) {
        const int idx = i * 256 + t;
        float s = 0.f;
#pragma unroll
        for (int c = 0; c < 8; ++c) s += src[c * 4096 + idx];
        kvb[(size_t)bh * 4096 + idx] = f2bf(s);
    }
    if (t < 64) {
        float s = 0.f;
#pragma unroll
        for (int c = 0; c < 8; ++c) s += ksp[((size_t)bh * 8 + c) * 64 + t];
        ksum[bh * 64 + t] = s;
    }
}

// ---------------------------------------------------------------------------
// MT[b][c][h*64+d] = sum_e kv[b,h,d,e] * wp[c, h*64+e]   (bf16 out)
// ---------------------------------------------------------------------------
__global__ __launch_bounds__(256) void gemm_M(
    const unsigned short* __restrict__ kvb,   // [64][4096]
    const unsigned short* __restrict__ wp,    // [512][512]
    unsigned short* __restrict__ MT)          // [8][512][512]
{
    const int bh = blockIdx.x, b = bh >> 3, h = bh & 7;
    const int t = threadIdx.x, w = t >> 6, lane = t & 63;
    const int ln = lane & 15, g = lane >> 4;

    float4v acc[8][4];
#pragma unroll
    for (int i = 0; i < 8; ++i)
#pragma unroll
        for (int j = 0; j < 4; ++j) acc[i][j] = {0.f, 0.f, 0.f, 0.f};

#pragma unroll
    for (int kk = 0; kk < 2; ++kk) {
        short8v a[8], bf[4];
#pragma unroll
        for (int i = 0; i < 8; ++i)
            a[i] = *reinterpret_cast<const short8v*>(
                wp + (size_t)(w * 128 + i * 16 + ln) * 512 + h * 64 + kk * 32 + g * 8);
#pragma unroll
        for (int j = 0; j < 4; ++j)
            bf[j] = *reinterpret_cast<const short8v*>(
                kvb + (size_t)bh * 4096 + (j * 16 + ln) * 64 + kk * 32 + g * 8);
#pragma unroll
        for (int i = 0; i < 8; ++i)
#pragma unroll
            for (int j = 0; j < 4; ++j)
                acc[i][j] = __builtin_amdgcn_mfma_f32_16x16x32_bf16(a[i], bf[j], acc[i][j], 0, 0, 0);
    }

#pragma unroll
    for (int i = 0; i < 8; ++i) {
        const int c0 = w * 128 + i * 16 + g * 4;
#pragma unroll
        for (int j = 0; j < 4; ++j) {
            const int d = j * 16 + ln;
#pragma unroll
            for (int r = 0; r < 4; ++r)
                MT[(size_t)b * 262144 + (size_t)(c0 + r) * 512 + h * 64 + d] =
                    f2bf(acc[i][j][r]);
        }
    }
}

// ---------------------------------------------------------------------------
// q' = q / (q . ksum_h + eps), in place (bf16)
// ---------------------------------------------------------------------------
__global__ __launch_bounds__(256) void q_scale(
    unsigned short* __restrict__ qkv, const float* __restrict__ ksum)
{
    __shared__ float kss[512];
    const int blk = blockIdx.x;          // 1024
    const int b = blk >> 7;
    const int t = threadIdx.x;
    kss[t] = ksum[b * 512 + t];
    kss[t + 256] = ksum[b * 512 + 256 + t];
    __syncthreads();

    const int row = blk * 32 + (t >> 3);
    const int h = t & 7;
    unsigned short* p = qkv + (size_t)row * QKVC + h * 64;

    ushort8v v[8];
#pragma unroll
    for (int s = 0; s < 8; ++s) v[s] = *reinterpret_cast<const ushort8v*>(p + s * 8);

    float den = EPSF;
#pragma unroll
    for (int s = 0; s < 8; ++s)
#pragma unroll
        for (int m = 0; m < 8; ++m)
            den += bf2f(v[s][m]) * kss[h * 64 + s * 8 + m];
    const float inv = 1.0f / den;

#pragma unroll
    for (int s = 0; s < 8; ++s) {
        ushort8v o;
#pragma unroll
        for (int m = 0; m < 8; ++m) o[m] = f2bf(bf2f(v[s][m]) * inv);
        *reinterpret_cast<ushort8v*>(p + s * 8) = o;
    }
}

// ---------------------------------------------------------------------------
// out = q' @ MT_b^T + bias  (f32 out), ring-3 (round-11 proven)
// ---------------------------------------------------------------------------
__global__ __launch_bounds__(512, 2) void gemm_out(
    const unsigned short* __restrict__ A,    // qkvb, lda 1536
    const unsigned short* __restrict__ Bt,   // MT [8][512][512]
    const float* __restrict__ bias,
    float* __restrict__ out)                 // [32768,512]
{
    constexpr int LDA = 1536, LDB = 512, NT = 8;
    __shared__ unsigned short ring[3][24576];

    const int t = threadIdx.x;
    const int orig = blockIdx.x;
    const int wg = (orig & 7) * 64 + (orig >> 3);   // nwg=512, %8==0
    const int bm = (wg >> 2) * 256;
    const int bn = (wg & 3) * 128;
    const unsigned short* Bm = Bt + (size_t)(bm >> 12) * 262144;

    const int w = t >> 6, lane = t & 63;
    const int ln = lane & 15, g = lane >> 4;
    const int wr = (w >> 1) * 64;
    const int wc = (w & 1) * 64;
    const int l7 = ln & 7;

    const int rs = t >> 3;
    const int ci = t & 7;
    const int swz = ci ^ (rs & 7);
    const unsigned short* As0 = A + (size_t)(bm + rs) * LDA + swz * 8;
    const unsigned short* As1 = A + (size_t)(bm + 64 + rs) * LDA + swz * 8;
    const unsigned short* As2 = A + (size_t)(bm + 128 + rs) * LDA + swz * 8;
    const unsigned short* As3 = A + (size_t)(bm + 192 + rs) * LDA + swz * 8;
    const unsigned short* Bs0 = Bm + (size_t)(bn + rs) * LDB + swz * 8;
    const unsigned short* Bs1 = Bm + (size_t)(bn + 64 + rs) * LDB + swz * 8;

#define STAGEO(Tt) do {                                                        \
        const int k0_ = (Tt) * 64;                                             \
        unsigned short* dA_ = &ring[(Tt) % 3][0];                              \
        unsigned short* dB_ = &ring[(Tt) % 3][16384];                          \
        llds16(As0 + k0_, dA_ + (size_t)t * 8);                                \
        llds16(As1 + k0_, dA_ + (size_t)(512 + t) * 8);                        \
        llds16(As2 + k0_, dA_ + (size_t)(1024 + t) * 8);                       \
        llds16(As3 + k0_, dA_ + (size_t)(1536 + t) * 8);                       \
        llds16(Bs0 + k0_, dB_ + (size_t)t * 8);                                \
        llds16(Bs1 + k0_, dB_ + (size_t)(512 + t) * 8);                        \
    } while (0)

    float4v acc[4][4];
#pragma unroll
    for (int i = 0; i < 4; ++i)
#pragma unroll
        for (int j = 0; j < 4; ++j) acc[i][j] = {0.f, 0.f, 0.f, 0.f};

    STAGEO(0);
    STAGEO(1);
    asm volatile("s_waitcnt vmcnt(6)" ::: "memory");
    __builtin_amdgcn_s_barrier();
    __builtin_amdgcn_sched_barrier(0);

#pragma unroll
    for (int T = 0; T < NT; ++T) {
        if (T + 2 < NT) STAGEO(T + 2);

        const unsigned short* base = &ring[T % 3][0];
        short8v a[4][2], b[4][2];
#pragma unroll
        for (int i = 0; i < 4; ++i)
#pragma unroll
            for (int kk = 0; kk < 2; ++kk) {
                const int row = wr + i * 16 + ln;
                a[i][kk] = *reinterpret_cast<const short8v*>(
                    base + row * 64 + (((kk * 4 + g) ^ l7) << 3));
            }
#pragma unroll
        for (int j = 0; j < 4; ++j)
#pragma unroll
            for (int kk = 0; kk < 2; ++kk) {
                const int row = wc + j * 16 + ln;
                b[j][kk] = *reinterpret_cast<const short8v*>(
                    base + 16384 + row * 64 + (((kk * 4 + g) ^ l7) << 3));
            }

        __builtin_amdgcn_s_setprio(1);
#pragma unroll
        for (int kk = 0; kk < 2; ++kk)
#pragma unroll
            for (int i = 0; i < 4; ++i)
#pragma unroll
                for (int j = 0; j < 4; ++j)
                    acc[i][j] = __builtin_amdgcn_mfma_f32_16x16x32_bf16(
                        a[i][kk], b[j][kk], acc[i][j], 0, 0, 0);
        __builtin_amdgcn_s_setprio(0);

        if (T + 1 < NT) {
            if (T + 2 < NT)
                asm volatile("s_waitcnt vmcnt(6)" ::: "memory");
            else
                asm volatile("s_waitcnt vmcnt(0)" ::: "memory");
            __builtin_amdgcn_s_barrier();
            __builtin_amdgcn_sched_barrier(0);
        }
    }
#undef STAGEO

#pragma unroll
    for (int i = 0; i < 4; ++i) {
        const int Rb = bm + wr + i * 16 + g * 4;
#pragma unroll
        for (int j = 0; j < 4; ++j) {
            const int Cc = bn + wc + j * 16 + ln;
            const float bv = bias[Cc];
#pragma unroll
            for (int r = 0; r < 4; ++r)
                out[(size_t)(Rb + r) * 512 + Cc] = acc[i][j][r] + bv;
        }
    }
}

// ---------------------------------------------------------------------------
extern "C" void kernel_launch(void* const* d_in, const int* in_sizes, int n_in,
                              void* d_out, int out_size, void* d_ws, size_t ws_size,
                              hipStream_t stream)
{
    const float* x      = (const float*)d_in[0];  // [8,4096,512]
    const float* w_qkv  = (const float*)d_in[1];  // [1536,512]
    const float* w_proj = (const float*)d_in[2];  // [512,512]
    const float* b_proj = (const float*)d_in[3];  // [512]
    float* out = (float*)d_out;

    char* ws = (char*)d_ws;
    unsigned short* qkvb = (unsigned short*)ws;                    // 96 MiB
    size_t off = (size_t)32768 * 1536 * 2;
    unsigned short* xb   = (unsigned short*)(ws + off); off += (size_t)32768 * 512 * 2;
    unsigned short* wqb  = (unsigned short*)(ws + off); off += (size_t)1536 * 512 * 2;
    unsigned short* wpb  = (unsigned short*)(ws + off); off += (size_t)512 * 512 * 2;
    float* kvp           = (float*)(ws + off);          off += (size_t)64 * 8 * 4096 * 4;
    float* ksp           = (float*)(ws + off);          off += (size_t)64 * 8 * 64 * 4;
    unsigned short* kvb  = (unsigned short*)(ws + off); off += (size_t)64 * 4096 * 2;
    float* ksumb         = (float*)(ws + off);          off += (size_t)64 * 64 * 4;
    unsigned short* MT   = (unsigned short*)(ws + off); off += (size_t)8 * 512 * 512 * 2;

    // 1) convert inputs to bf16
    cvt_f32_bf16<<<dim3((32768 * 512 / 8 + 255) / 256), dim3(256), 0, stream>>>(x, xb, 32768 * 512 / 8);
    cvt_weights<<<dim3(((1536 * 512 + 512 * 512) / 8 + 255) / 256), dim3(256), 0, stream>>>(
        w_qkv, w_proj, wqb, wpb);

    // 2) qkv = elu1(x @ w_qkv^T) (elu on cols<1024), bf16 out — ring-3, 32x32 MFMA
    gemm_qkv<<<dim3(1536), dim3(512), 0, stream>>>(xb, wqb, qkvb);

    // 3) kv partials (v4 MFMA) + reduce
    kv_part<<<dim3(64, 8), dim3(256), 0, stream>>>(qkvb, kvp, ksp);
    kv_reduce<<<dim3(64), dim3(256), 0, stream>>>(kvp, ksp, kvb, ksumb);

    // 4) MT_b = (kv_h @ wp_h^T) stacked, per batch
    gemm_M<<<dim3(64), dim3(256), 0, stream>>>(kvb, wpb, MT);

    // 5) q' = q / (q.ksum + eps), in place
    q_scale<<<dim3(1024), dim3(256), 0, stream>>>(qkvb, ksumb);

    // 6) out = q' @ MT_b^T + bias (f32) — ring-3
    gemm_out<<<dim3(512), dim3(512), 0, stream>>>(qkvb, MT, b_proj, out);
}

// Round 18
// 166.136 us; speedup vs baseline: 1.0470x; 1.0470x over previous
//
#include <hip/hip_runtime.h>
#include <hip/hip_bf16.h>
#include <math.h>

#define EPSF 1e-6f

constexpr int Bc = 8;
constexpr int Nc = 4096;
constexpr int Dc = 512;
constexpr int QKVC = 3 * Dc;  // 1536

typedef __attribute__((ext_vector_type(8))) short short8v;
typedef __attribute__((ext_vector_type(8))) unsigned short ushort8v;
typedef __attribute__((ext_vector_type(4))) float float4v;

__device__ __forceinline__ unsigned short f2bf(float f) {
    union { float f; unsigned int u; } v; v.f = f;
    unsigned int u = v.u;
    return (unsigned short)((u + 0x7fffu + ((u >> 16) & 1u)) >> 16);
}
__device__ __forceinline__ float bf2f(unsigned short h) {
    union { unsigned int u; float f; } v; v.u = ((unsigned int)h) << 16;
    return v.f;
}

typedef __attribute__((address_space(1))) const void gvoid_t;
typedef __attribute__((address_space(3))) void lvoid_t;
__device__ __forceinline__ void llds16(const void* g, void* l) {
    __builtin_amdgcn_global_load_lds((gvoid_t*)g, (lvoid_t*)l, 16, 0, 0);
}

// ---------------------------------------------------------------------------
// f32 -> bf16 conversion, 8 elems/thread
// ---------------------------------------------------------------------------
__global__ __launch_bounds__(256) void cvt_f32_bf16(
    const float* __restrict__ in, unsigned short* __restrict__ out, int n8)
{
    int i = blockIdx.x * 256 + threadIdx.x;
    if (i >= n8) return;
    float4 a = reinterpret_cast<const float4*>(in)[2 * i];
    float4 b = reinterpret_cast<const float4*>(in)[2 * i + 1];
    ushort8v o;
    o[0] = f2bf(a.x); o[1] = f2bf(a.y); o[2] = f2bf(a.z); o[3] = f2bf(a.w);
    o[4] = f2bf(b.x); o[5] = f2bf(b.y); o[6] = f2bf(b.z); o[7] = f2bf(b.w);
    reinterpret_cast<ushort8v*>(out)[i] = o;
}

// combined weight convert: w_qkv (1536x512) then w_proj (512x512)
__global__ __launch_bounds__(256) void cvt_weights(
    const float* __restrict__ wq, const float* __restrict__ wp,
    unsigned short* __restrict__ wqo, unsigned short* __restrict__ wpo)
{
    const int i = blockIdx.x * 256 + threadIdx.x;
    const int NQ = 1536 * 512 / 8;            // 98304
    const float* src; unsigned short* dst; int idx;
    if (i < NQ) { src = wq; dst = wqo; idx = i; }
    else        { src = wp; dst = wpo; idx = i - NQ; }
    float4 a = reinterpret_cast<const float4*>(src)[2 * idx];
    float4 b = reinterpret_cast<const float4*>(src)[2 * idx + 1];
    ushort8v o;
    o[0] = f2bf(a.x); o[1] = f2bf(a.y); o[2] = f2bf(a.z); o[3] = f2bf(a.w);
    o[4] = f2bf(b.x); o[5] = f2bf(b.y); o[6] = f2bf(b.z); o[7] = f2bf(b.w);
    reinterpret_cast<ushort8v*>(dst)[idx] = o;
}

// ---------------------------------------------------------------------------
// qkv GEMM (ring-3, best measured: 83us, conflicts=0) — round-11/15 verbatim
// ---------------------------------------------------------------------------
__global__ __launch_bounds__(512, 2) void gemm_qkv(
    const unsigned short* __restrict__ A,    // [32768,512]
    const unsigned short* __restrict__ Bm,   // [1536,512]
    unsigned short* __restrict__ Cout)       // [32768,1536]
{
    constexpr int LDA = 512, LDB = 512, LDC = 1536;
    constexpr int NT = 8;
    __shared__ unsigned short ring[3][24576];

    const int t = threadIdx.x;
    const int orig = blockIdx.x;
    const int wg = (orig & 7) * 192 + (orig >> 3);   // nwg=1536, %8==0
    const int bm = (wg / 12) * 256;
    const int bn = (wg % 12) * 128;

    const int w = t >> 6, lane = t & 63;
    const int ln = lane & 15, g = lane >> 4;
    const int wr = (w >> 1) * 64;
    const int wc = (w & 1) * 64;
    const int l7 = ln & 7;

    const int rs = t >> 3;
    const int ci = t & 7;
    const int swz = ci ^ (rs & 7);
    const unsigned short* As0 = A + (size_t)(bm + rs) * LDA + swz * 8;
    const unsigned short* As1 = A + (size_t)(bm + 64 + rs) * LDA + swz * 8;
    const unsigned short* As2 = A + (size_t)(bm + 128 + rs) * LDA + swz * 8;
    const unsigned short* As3 = A + (size_t)(bm + 192 + rs) * LDA + swz * 8;
    const unsigned short* Bs0 = Bm + (size_t)(bn + rs) * LDB + swz * 8;
    const unsigned short* Bs1 = Bm + (size_t)(bn + 64 + rs) * LDB + swz * 8;

#define STAGEQ(Tt) do {                                                        \
        const int k0_ = (Tt) * 64;                                             \
        unsigned short* dA_ = &ring[(Tt) % 3][0];                              \
        unsigned short* dB_ = &ring[(Tt) % 3][16384];                          \
        llds16(As0 + k0_, dA_ + (size_t)t * 8);                                \
        llds16(As1 + k0_, dA_ + (size_t)(512 + t) * 8);                        \
        llds16(As2 + k0_, dA_ + (size_t)(1024 + t) * 8);                       \
        llds16(As3 + k0_, dA_ + (size_t)(1536 + t) * 8);                       \
        llds16(Bs0 + k0_, dB_ + (size_t)t * 8);                                \
        llds16(Bs1 + k0_, dB_ + (size_t)(512 + t) * 8);                        \
    } while (0)

    float4v acc[4][4];
#pragma unroll
    for (int i = 0; i < 4; ++i)
#pragma unroll
        for (int j = 0; j < 4; ++j) acc[i][j] = {0.f, 0.f, 0.f, 0.f};

    STAGEQ(0);
    STAGEQ(1);
    asm volatile("s_waitcnt vmcnt(6)" ::: "memory");
    __builtin_amdgcn_s_barrier();
    __builtin_amdgcn_sched_barrier(0);

#pragma unroll
    for (int T = 0; T < NT; ++T) {
        if (T + 2 < NT) STAGEQ(T + 2);

        const unsigned short* base = &ring[T % 3][0];
        short8v a[4][2], b[4][2];
#pragma unroll
        for (int i = 0; i < 4; ++i)
#pragma unroll
            for (int kk = 0; kk < 2; ++kk) {
                const int row = wr + i * 16 + ln;
                a[i][kk] = *reinterpret_cast<const short8v*>(
                    base + row * 64 + (((kk * 4 + g) ^ l7) << 3));
            }
#pragma unroll
        for (int j = 0; j < 4; ++j)
#pragma unroll
            for (int kk = 0; kk < 2; ++kk) {
                const int row = wc + j * 16 + ln;
                b[j][kk] = *reinterpret_cast<const short8v*>(
                    base + 16384 + row * 64 + (((kk * 4 + g) ^ l7) << 3));
            }

        __builtin_amdgcn_s_setprio(1);
#pragma unroll
        for (int kk = 0; kk < 2; ++kk)
#pragma unroll
            for (int i = 0; i < 4; ++i)
#pragma unroll
                for (int j = 0; j < 4; ++j)
                    acc[i][j] = __builtin_amdgcn_mfma_f32_16x16x32_bf16(
                        a[i][kk], b[j][kk], acc[i][j], 0, 0, 0);
        __builtin_amdgcn_s_setprio(0);

        if (T + 1 < NT) {
            if (T + 2 < NT)
                asm volatile("s_waitcnt vmcnt(6)" ::: "memory");
            else
                asm volatile("s_waitcnt vmcnt(0)" ::: "memory");
            __builtin_amdgcn_s_barrier();
            __builtin_amdgcn_sched_barrier(0);
        }
    }
#undef STAGEQ

#pragma unroll
    for (int i = 0; i < 4; ++i) {
        const int Rb = bm + wr + i * 16 + g * 4;
#pragma unroll
        for (int j = 0; j < 4; ++j) {
            const int Cc = bn + wc + j * 16 + ln;
            const bool do_elu = (Cc < 1024);
#pragma unroll
            for (int r = 0; r < 4; ++r) {
                float v = acc[i][j][r];
                if (do_elu) v = (v > 0.f) ? (v + 1.0f + EPSF) : (expf(v) + EPSF);
                Cout[(size_t)(Rb + r) * LDC + Cc] = f2bf(v);
            }
        }
    }
}

// ---------------------------------------------------------------------------
// kv partials v4 (round-15 proven): MFMA on transposed bf16 tiles
// ---------------------------------------------------------------------------
__global__ __launch_bounds__(256) void kv_part(
    const unsigned short* __restrict__ qkv,
    float* __restrict__ kvp, float* __restrict__ ksp)
{
    const int bh = blockIdx.x, chunk = blockIdx.y;
    const int b = bh >> 3, h = bh & 7;

    __shared__ unsigned short ktT[64 * 72];
    __shared__ unsigned short vtT[64 * 72];
    __shared__ float ksl[16][64];

    const int t = threadIdx.x;
    const int w = t >> 6, lane = t & 63;
    const int ln = lane & 15, g = lane >> 4;

    const bool isK = (t < 128);
    const int ts = isK ? t : t - 128;
    const int slot = ts & 7;
    const int ng = ts >> 3;

    const size_t base = ((size_t)b * Nc + (size_t)chunk * 512) * QKVC + h * 64
                      + (isK ? Dc : 2 * Dc) + (size_t)slot * 8;

    unsigned short* Tdst = isK ? ktT : vtT;

    float4v acc[4];
#pragma unroll
    for (int j = 0; j < 4; ++j) acc[j] = {0.f, 0.f, 0.f, 0.f};
    float ks8[8] = {};

    for (int it = 0; it < 8; ++it) {
        {
            const unsigned short* src = qkv + base + (size_t)(it * 64 + 4 * ng) * QKVC;
            ushort8v r0 = *reinterpret_cast<const ushort8v*>(src);
            ushort8v r1 = *reinterpret_cast<const ushort8v*>(src + QKVC);
            ushort8v r2 = *reinterpret_cast<const ushort8v*>(src + 2 * QKVC);
            ushort8v r3 = *reinterpret_cast<const ushort8v*>(src + 3 * QKVC);
#pragma unroll
            for (int i = 0; i < 8; ++i) {
                const int d = 8 * slot + i;
                unsigned long long pk = (unsigned long long)r0[i]
                    | ((unsigned long long)r1[i] << 16)
                    | ((unsigned long long)r2[i] << 32)
                    | ((unsigned long long)r3[i] << 48);
                *reinterpret_cast<unsigned long long*>(&Tdst[d * 72 + 4 * ng]) = pk;
                if (isK) ks8[i] += bf2f(r0[i]) + bf2f(r1[i]) + bf2f(r2[i]) + bf2f(r3[i]);
            }
        }
        __syncthreads();

        short8v afr[2], bfr[4][2];
#pragma unroll
        for (int kk = 0; kk < 2; ++kk)
            afr[kk] = *reinterpret_cast<const short8v*>(
                &ktT[(w * 16 + ln) * 72 + kk * 32 + g * 8]);
#pragma unroll
        for (int j = 0; j < 4; ++j)
#pragma unroll
            for (int kk = 0; kk < 2; ++kk)
                bfr[j][kk] = *reinterpret_cast<const short8v*>(
                    &vtT[(j * 16 + ln) * 72 + kk * 32 + g * 8]);
#pragma unroll
        for (int kk = 0; kk < 2; ++kk)
#pragma unroll
            for (int j = 0; j < 4; ++j)
                acc[j] = __builtin_amdgcn_mfma_f32_16x16x32_bf16(
                    afr[kk], bfr[j][kk], acc[j], 0, 0, 0);
        __syncthreads();
    }

    float* kvpp = kvp + ((size_t)bh * 8 + chunk) * 4096;
#pragma unroll
    for (int j = 0; j < 4; ++j)
#pragma unroll
        for (int r = 0; r < 4; ++r)
            kvpp[(w * 16 + g * 4 + r) * 64 + j * 16 + ln] = acc[j][r];

    if (isK) {
#pragma unroll
        for (int i = 0; i < 8; ++i) ksl[ng][8 * slot + i] = ks8[i];
    }
    __syncthreads();
    if (t < 64) {
        float s = 0.f;
#pragma unroll
        for (int c = 0; c < 16; ++c) s += ksl[c][t];
        ksp[((size_t)bh * 8 + chunk) * 64 + t] = s;
    }
}

// ---------------------------------------------------------------------------
// reduce 8 chunk-partials -> kvb (bf16, [d][e]) + ksum (f32)
// ---------------------------------------------------------------------------
__global__ __launch_bounds__(256) void kv_reduce(
    const float* __restrict__ kvp, const float* __restrict__ ksp,
    unsigned short* __restrict__ kvb, float* __restrict__ ksum)
{
    const int bh = blockIdx.x, t = threadIdx.x;
    const float* src = kvp + (size_t)bh * 8 * 4096;
#pragma unroll
    for (int i = 0; i < 16; ++i) {
        const int idx = i * 256 + t;
        float s = 0.f;
#pragma unroll
        for (int c = 0; c < 8; ++c) s += src[c * 4096 + idx];
        kvb[(size_t)bh * 4096 + idx] = f2bf(s);
    }
    if (t < 64) {
        float s = 0.f;
#pragma unroll
        for (int c = 0; c < 8; ++c) s += ksp[((size_t)bh * 8 + c) * 64 + t];
        ksum[bh * 64 + t] = s;
    }
}

// ---------------------------------------------------------------------------
// MT[b][c][h*64+d] = sum_e kv[b,h,d,e] * wp[c, h*64+e]   (bf16 out)
// ---------------------------------------------------------------------------
__global__ __launch_bounds__(256) void gemm_M(
    const unsigned short* __restrict__ kvb,   // [64][4096]
    const unsigned short* __restrict__ wp,    // [512][512]
    unsigned short* __restrict__ MT)          // [8][512][512]
{
    const int bh = blockIdx.x, b = bh >> 3, h = bh & 7;
    const int t = threadIdx.x, w = t >> 6, lane = t & 63;
    const int ln = lane & 15, g = lane >> 4;

    float4v acc[8][4];
#pragma unroll
    for (int i = 0; i < 8; ++i)
#pragma unroll
        for (int j = 0; j < 4; ++j) acc[i][j] = {0.f, 0.f, 0.f, 0.f};

#pragma unroll
    for (int kk = 0; kk < 2; ++kk) {
        short8v a[8], bf[4];
#pragma unroll
        for (int i = 0; i < 8; ++i)
            a[i] = *reinterpret_cast<const short8v*>(
                wp + (size_t)(w * 128 + i * 16 + ln) * 512 + h * 64 + kk * 32 + g * 8);
#pragma unroll
        for (int j = 0; j < 4; ++j)
            bf[j] = *reinterpret_cast<const short8v*>(
                kvb + (size_t)bh * 4096 + (j * 16 + ln) * 64 + kk * 32 + g * 8);
#pragma unroll
        for (int i = 0; i < 8; ++i)
#pragma unroll
            for (int j = 0; j < 4; ++j)
                acc[i][j] = __builtin_amdgcn_mfma_f32_16x16x32_bf16(a[i], bf[j], acc[i][j], 0, 0, 0);
    }

#pragma unroll
    for (int i = 0; i < 8; ++i) {
        const int c0 = w * 128 + i * 16 + g * 4;
#pragma unroll
        for (int j = 0; j < 4; ++j) {
            const int d = j * 16 + ln;
#pragma unroll
            for (int r = 0; r < 4; ++r)
                MT[(size_t)b * 262144 + (size_t)(c0 + r) * 512 + h * 64 + d] =
                    f2bf(acc[i][j][r]);
        }
    }
}

// ---------------------------------------------------------------------------
// q' = q / (q . ksum_h + eps), in place (bf16)
// ---------------------------------------------------------------------------
__global__ __launch_bounds__(256) void q_scale(
    unsigned short* __restrict__ qkv, const float* __restrict__ ksum)
{
    __shared__ float kss[512];
    const int blk = blockIdx.x;          // 1024
    const int b = blk >> 7;
    const int t = threadIdx.x;
    kss[t] = ksum[b * 512 + t];
    kss[t + 256] = ksum[b * 512 + 256 + t];
    __syncthreads();

    const int row = blk * 32 + (t >> 3);
    const int h = t & 7;
    unsigned short* p = qkv + (size_t)row * QKVC + h * 64;

    ushort8v v[8];
#pragma unroll
    for (int s = 0; s < 8; ++s) v[s] = *reinterpret_cast<const ushort8v*>(p + s * 8);

    float den = EPSF;
#pragma unroll
    for (int s = 0; s < 8; ++s)
#pragma unroll
        for (int m = 0; m < 8; ++m)
            den += bf2f(v[s][m]) * kss[h * 64 + s * 8 + m];
    const float inv = 1.0f / den;

#pragma unroll
    for (int s = 0; s < 8; ++s) {
        ushort8v o;
#pragma unroll
        for (int m = 0; m < 8; ++m) o[m] = f2bf(bf2f(v[s][m]) * inv);
        *reinterpret_cast<ushort8v*>(p + s * 8) = o;
    }
}

// ---------------------------------------------------------------------------
// out = q' @ MT_b^T + bias  (f32 out), ring-3 (round-11 proven)
// ---------------------------------------------------------------------------
__global__ __launch_bounds__(512, 2) void gemm_out(
    const unsigned short* __restrict__ A,    // qkvb, lda 1536
    const unsigned short* __restrict__ Bt,   // MT [8][512][512]
    const float* __restrict__ bias,
    float* __restrict__ out)                 // [32768,512]
{
    constexpr int LDA = 1536, LDB = 512, NT = 8;
    __shared__ unsigned short ring[3][24576];

    const int t = threadIdx.x;
    const int orig = blockIdx.x;
    const int wg = (orig & 7) * 64 + (orig >> 3);   // nwg=512, %8==0
    const int bm = (wg >> 2) * 256;
    const int bn = (wg & 3) * 128;
    const unsigned short* Bm = Bt + (size_t)(bm >> 12) * 262144;

    const int w = t >> 6, lane = t & 63;
    const int ln = lane & 15, g = lane >> 4;
    const int wr = (w >> 1) * 64;
    const int wc = (w & 1) * 64;
    const int l7 = ln & 7;

    const int rs = t >> 3;
    const int ci = t & 7;
    const int swz = ci ^ (rs & 7);
    const unsigned short* As0 = A + (size_t)(bm + rs) * LDA + swz * 8;
    const unsigned short* As1 = A + (size_t)(bm + 64 + rs) * LDA + swz * 8;
    const unsigned short* As2 = A + (size_t)(bm + 128 + rs) * LDA + swz * 8;
    const unsigned short* As3 = A + (size_t)(bm + 192 + rs) * LDA + swz * 8;
    const unsigned short* Bs0 = Bm + (size_t)(bn + rs) * LDB + swz * 8;
    const unsigned short* Bs1 = Bm + (size_t)(bn + 64 + rs) * LDB + swz * 8;

#define STAGEO(Tt) do {                                                        \
        const int k0_ = (Tt) * 64;                                             \
        unsigned short* dA_ = &ring[(Tt) % 3][0];                              \
        unsigned short* dB_ = &ring[(Tt) % 3][16384];                          \
        llds16(As0 + k0_, dA_ + (size_t)t * 8);                                \
        llds16(As1 + k0_, dA_ + (size_t)(512 + t) * 8);                        \
        llds16(As2 + k0_, dA_ + (size_t)(1024 + t) * 8);                       \
        llds16(As3 + k0_, dA_ + (size_t)(1536 + t) * 8);                       \
        llds16(Bs0 + k0_, dB_ + (size_t)t * 8);                                \
        llds16(Bs1 + k0_, dB_ + (size_t)(512 + t) * 8);                        \
    } while (0)

    float4v acc[4][4];
#pragma unroll
    for (int i = 0; i < 4; ++i)
#pragma unroll
        for (int j = 0; j < 4; ++j) acc[i][j] = {0.f, 0.f, 0.f, 0.f};

    STAGEO(0);
    STAGEO(1);
    asm volatile("s_waitcnt vmcnt(6)" ::: "memory");
    __builtin_amdgcn_s_barrier();
    __builtin_amdgcn_sched_barrier(0);

#pragma unroll
    for (int T = 0; T < NT; ++T) {
        if (T + 2 < NT) STAGEO(T + 2);

        const unsigned short* base = &ring[T % 3][0];
        short8v a[4][2], b[4][2];
#pragma unroll
        for (int i = 0; i < 4; ++i)
#pragma unroll
            for (int kk = 0; kk < 2; ++kk) {
                const int row = wr + i * 16 + ln;
                a[i][kk] = *reinterpret_cast<const short8v*>(
                    base + row * 64 + (((kk * 4 + g) ^ l7) << 3));
            }
#pragma unroll
        for (int j = 0; j < 4; ++j)
#pragma unroll
            for (int kk = 0; kk < 2; ++kk) {
                const int row = wc + j * 16 + ln;
                b[j][kk] = *reinterpret_cast<const short8v*>(
                    base + 16384 + row * 64 + (((kk * 4 + g) ^ l7) << 3));
            }

        __builtin_amdgcn_s_setprio(1);
#pragma unroll
        for (int kk = 0; kk < 2; ++kk)
#pragma unroll
            for (int i = 0; i < 4; ++i)
#pragma unroll
                for (int j = 0; j < 4; ++j)
                    acc[i][j] = __builtin_amdgcn_mfma_f32_16x16x32_bf16(
                        a[i][kk], b[j][kk], acc[i][j], 0, 0, 0);
        __builtin_amdgcn_s_setprio(0);

        if (T + 1 < NT) {
            if (T + 2 < NT)
                asm volatile("s_waitcnt vmcnt(6)" ::: "memory");
            else
                asm volatile("s_waitcnt vmcnt(0)" ::: "memory");
            __builtin_amdgcn_s_barrier();
            __builtin_amdgcn_sched_barrier(0);
        }
    }
#undef STAGEO

#pragma unroll
    for (int i = 0; i < 4; ++i) {
        const int Rb = bm + wr + i * 16 + g * 4;
#pragma unroll
        for (int j = 0; j < 4; ++j) {
            const int Cc = bn + wc + j * 16 + ln;
            const float bv = bias[Cc];
#pragma unroll
            for (int r = 0; r < 4; ++r)
                out[(size_t)(Rb + r) * 512 + Cc] = acc[i][j][r] + bv;
        }
    }
}

// ---------------------------------------------------------------------------
extern "C" void kernel_launch(void* const* d_in, const int* in_sizes, int n_in,
                              void* d_out, int out_size, void* d_ws, size_t ws_size,
                              hipStream_t stream)
{
    const float* x      = (const float*)d_in[0];  // [8,4096,512]
    const float* w_qkv  = (const float*)d_in[1];  // [1536,512]
    const float* w_proj = (const float*)d_in[2];  // [512,512]
    const float* b_proj = (const float*)d_in[3];  // [512]
    float* out = (float*)d_out;

    char* ws = (char*)d_ws;
    unsigned short* qkvb = (unsigned short*)ws;                    // 96 MiB
    size_t off = (size_t)32768 * 1536 * 2;
    unsigned short* xb   = (unsigned short*)(ws + off); off += (size_t)32768 * 512 * 2;
    unsigned short* wqb  = (unsigned short*)(ws + off); off += (size_t)1536 * 512 * 2;
    unsigned short* wpb  = (unsigned short*)(ws + off); off += (size_t)512 * 512 * 2;
    float* kvp           = (float*)(ws + off);          off += (size_t)64 * 8 * 4096 * 4;
    float* ksp           = (float*)(ws + off);          off += (size_t)64 * 8 * 64 * 4;
    unsigned short* kvb  = (unsigned short*)(ws + off); off += (size_t)64 * 4096 * 2;
    float* ksumb         = (float*)(ws + off);          off += (size_t)64 * 64 * 4;
    unsigned short* MT   = (unsigned short*)(ws + off); off += (size_t)8 * 512 * 512 * 2;

    // 1) convert inputs to bf16
    cvt_f32_bf16<<<dim3((32768 * 512 / 8 + 255) / 256), dim3(256), 0, stream>>>(x, xb, 32768 * 512 / 8);
    cvt_weights<<<dim3(((1536 * 512 + 512 * 512) / 8 + 255) / 256), dim3(256), 0, stream>>>(
        w_qkv, w_proj, wqb, wpb);

    // 2) qkv = elu1(x @ w_qkv^T) (elu on cols<1024), bf16 out — ring-3
    gemm_qkv<<<dim3(1536), dim3(512), 0, stream>>>(xb, wqb, qkvb);

    // 3) kv partials (v4 MFMA) + reduce
    kv_part<<<dim3(64, 8), dim3(256), 0, stream>>>(qkvb, kvp, ksp);
    kv_reduce<<<dim3(64), dim3(256), 0, stream>>>(kvp, ksp, kvb, ksumb);

    // 4) MT_b = (kv_h @ wp_h^T) stacked, per batch
    gemm_M<<<dim3(64), dim3(256), 0, stream>>>(kvb, wpb, MT);

    // 5) q' = q / (q.ksum + eps), in place
    q_scale<<<dim3(1024), dim3(256), 0, stream>>>(qkvb, ksumb);

    // 6) out = q' @ MT_b^T + bias (f32) — ring-3
    gemm_out<<<dim3(512), dim3(512), 0, stream>>>(qkvb, MT, b_proj, out);
}